// Round 5
// baseline (345.827 us; speedup 1.0000x reference)
//
#include <hip/hip_runtime.h>

#define NU 8192
#define NI 8192
#define DD 128

typedef float fx4 __attribute__((ext_vector_type(4)));
typedef int   ix4 __attribute__((ext_vector_type(4)));
typedef short bx8 __attribute__((ext_vector_type(8)));
typedef short sx4 __attribute__((ext_vector_type(4)));

__device__ __forceinline__ short f2bf(float f) {
  unsigned u = __float_as_uint(f);
  u = (u + 0x7FFFu + ((u >> 16) & 1u)) >> 16;   // RNE f32 -> bf16
  return (short)u;
}
__device__ __forceinline__ float lrelu(float x) { return fmaxf(x, 0.2f * x); }
// order-preserving float<->uint encode for atomicMax (deterministic: max is assoc/comm)
__device__ __forceinline__ unsigned fenc(float f) {
  unsigned u = __float_as_uint(f);
  return (u >> 31) ? ~u : (u | 0x80000000u);
}
__device__ __forceinline__ float fdec(unsigned u) {
  return (u >> 31) ? __uint_as_float(u & 0x7FFFFFFFu) : __uint_as_float(~u);
}

// ---- K1: v1[j] = sum_k a[k]*W[k][j] ; v2[j] = sum_k a[128+k]*W[k][j]; init mxenc
__global__ void k_vecs(const float* __restrict__ W, const float* __restrict__ a,
                       float* __restrict__ v1, float* __restrict__ v2,
                       unsigned* __restrict__ mxenc) {
  int j = threadIdx.x;  // 128 threads
  if (j == 0) mxenc[0] = 0u;
  float s1 = 0.f, s2 = 0.f;
  for (int k = 0; k < DD; ++k) {
    float w = W[k * DD + j];
    s1 += a[k] * w;
    s2 += a[DD + k] * w;
  }
  v1[j] = s1; v2[j] = s2;
}

// ---- K2: a1[u]=h_u·v1 ; a2[i]=h_i·v2 ; E1=exp(a2), E2=exp(0.2 a2); atomicMax a2
__global__ __launch_bounds__(256) void k_rowdots(
    const float* __restrict__ hU, const float* __restrict__ hI,
    const float* __restrict__ v1, const float* __restrict__ v2,
    float* __restrict__ a1, float* __restrict__ a2,
    float* __restrict__ e1, float* __restrict__ e2,
    unsigned* __restrict__ mxenc) {
  __shared__ float red[256];
  int g = blockIdx.x * 256 + threadIdx.x;
  const float* h; const float* v; int row;
  bool isU = (g < NU);
  if (isU) { h = hU; v = v1; row = g; }
  else     { h = hI; v = v2; row = g - NU; }
  const fx4* hv = (const fx4*)(h + (size_t)row * DD);
  const fx4* vv = (const fx4*)v;
  float s = 0.f;
#pragma unroll
  for (int q = 0; q < DD / 4; ++q) {
    fx4 hq = hv[q], vq = vv[q];
    s += hq[0]*vq[0] + hq[1]*vq[1] + hq[2]*vq[2] + hq[3]*vq[3];
  }
  if (isU) { a1[row] = s; return; }           // blocks 0..31 all-user: uniform exit
  a2[row] = s;
  e1[row] = __expf(s);
  e2[row] = __expf(0.2f * s);
  red[threadIdx.x] = s;
  __syncthreads();
  for (int st = 128; st > 0; st >>= 1) {
    if (threadIdx.x < st) red[threadIdx.x] = fmaxf(red[threadIdx.x], red[threadIdx.x + st]);
    __syncthreads();
  }
  if (threadIdx.x == 0) atomicMax(mxenc, fenc(red[0]));
}

// ---- K4: WiT[k][i] (bf16) = Wi[i][k] = sum_j h_i[i][j]*W[k][j]
__global__ __launch_bounds__(256) void k_wit(const float* __restrict__ hI,
                                             const float* __restrict__ W,
                                             short* __restrict__ WiT) {
  __shared__ float Wl[128 * 128];
  const int tid = threadIdx.x;
#pragma unroll
  for (int it = 0; it < 16; ++it) {
    int idx = it * 1024 + tid * 4;
    *(fx4*)(Wl + idx) = *(const fx4*)(W + idx);
  }
  __syncthreads();
  const int i0 = blockIdx.x * 64;
  const int rg = tid & 15;
  const int kg = tid >> 4;
  const int r0 = i0 + rg * 4;
  const int k0 = kg * 8;
  float acc[4][8];
#pragma unroll
  for (int r = 0; r < 4; ++r)
#pragma unroll
    for (int c = 0; c < 8; ++c) acc[r][c] = 0.f;
  for (int j = 0; j < 128; j += 4) {
    fx4 wv[8], hv[4];
#pragma unroll
    for (int c = 0; c < 8; ++c) wv[c] = *(const fx4*)(Wl + (k0 + c) * 128 + j);
#pragma unroll
    for (int r = 0; r < 4; ++r) hv[r] = *(const fx4*)(hI + (size_t)(r0 + r) * DD + j);
#pragma unroll
    for (int r = 0; r < 4; ++r)
#pragma unroll
      for (int c = 0; c < 8; ++c)
        acc[r][c] += hv[r][0]*wv[c][0] + hv[r][1]*wv[c][1] + hv[r][2]*wv[c][2] + hv[r][3]*wv[c][3];
  }
#pragma unroll
  for (int c = 0; c < 8; ++c) {
    sx4 pk;
#pragma unroll
    for (int r = 0; r < 4; ++r) pk[r] = f2bf(acc[r][c]);
    *(sx4*)(WiT + (size_t)(k0 + c) * NI + r0) = pk;
  }
}

// ---- K5a v3: stream adj once -> bitmask + rinv. 1 row/block, 512 thr, low VGPR.
__global__ __launch_bounds__(512, 4) void k_phaseA(
    const int* __restrict__ adj, const float* __restrict__ a1g,
    const float* __restrict__ e1g, const float* __restrict__ e2g,
    const unsigned* __restrict__ mxenc,
    float* __restrict__ rinv, unsigned short* __restrict__ mask16)
{
  const int row  = blockIdx.x;
  const int tid  = threadIdx.x;
  const int lane = tid & 63;
  const int wv   = tid >> 6;
  const float A  = a1g[row];
  const float C  = lrelu(A + fdec(mxenc[0]));
  const float K1 = __expf(A - C);
  const float K2 = __expf(0.2f * A - C);
  const float T1 = __expf(-A);          // sel <=> E1[i] > T1 <=> a1+a2 > 0
  const int i0 = tid * 16;
  const size_t base = (size_t)row * NI + i0;
  ix4 m[4]; fx4 E1[4], E2[4];
#pragma unroll
  for (int q = 0; q < 4; ++q) {
    m[q]  = *(const ix4*)(adj + base + q * 4);
    E1[q] = *(const fx4*)(e1g + i0 + q * 4);
    E2[q] = *(const fx4*)(e2g + i0 + q * 4);
  }
  unsigned hw = 0u;
  float s1 = 0.f, s2 = 0.f;
#pragma unroll
  for (int q = 0; q < 4; ++q) {
#pragma unroll
    for (int e = 0; e < 4; ++e) {
      const bool mm = (m[q][e] != 0);
      const bool sel = (E1[q][e] > T1);
      if (mm) hw |= (1u << (q * 4 + e));
      s1 += (mm && sel)  ? E1[q][e] : 0.f;
      s2 += (mm && !sel) ? E2[q][e] : 0.f;
    }
  }
  mask16[(size_t)row * 512 + tid] = (unsigned short)hw;
  float ps = K1 * s1 + K2 * s2;
#pragma unroll
  for (int st = 1; st < 64; st <<= 1) ps += __shfl_xor(ps, st, 64);
  __shared__ float lp[8];
  if (lane == 0) lp[wv] = ps;
  __syncthreads();
  if (tid == 0) {
    float l = 0.f;
#pragma unroll
    for (int w = 0; w < 8; ++w) l += lp[w];
    rinv[row] = (l > 0.f) ? (1.f / l) : 0.f;
  }
}

// ---- K5b: pure streaming alpha writer. wave g covers row g>>1, half (g&1)*4096.
// Every store instruction = 64 lanes x 16B contiguous = 1KB full lines.
__global__ __launch_bounds__(512, 4) void k_alpha(
    const unsigned* __restrict__ mask, const float* __restrict__ a1g,
    const unsigned* __restrict__ mxenc, const float* __restrict__ rinv,
    const float* __restrict__ e1g, const float* __restrict__ e2g,
    float* __restrict__ alphap)
{
  const int tid  = threadIdx.x;
  const int lane = tid & 63;
  const int wv   = tid >> 6;
  const int g    = blockIdx.x * 8 + wv;
  const int row  = g >> 1;
  const int half = (g & 1) << 12;
  const float A  = a1g[row];
  const float C  = lrelu(A + fdec(mxenc[0]));
  const float ri = rinv[row];
  const float K1r = __expf(A - C) * ri;
  const float K2r = __expf(0.2f * A - C) * ri;
  const float T1  = __expf(-A);
  const unsigned* mrow = mask + (size_t)row * 256 + (half >> 5);
  const size_t arow = (size_t)row * NI + half;
  const int l4 = lane * 4;
  const int ws = (lane & 7) * 4;
#pragma unroll 4
  for (int k = 0; k < 16; ++k) {
    const int i0 = k * 256 + l4;
    const unsigned nib = (mrow[k * 8 + (lane >> 3)] >> ws) & 0xFu;
    const fx4 e1v = *(const fx4*)(e1g + half + i0);
    const fx4 e2v = *(const fx4*)(e2g + half + i0);
    fx4 o;
#pragma unroll
    for (int j = 0; j < 4; ++j) {
      const float val = (e1v[j] > T1) ? e1v[j] * K1r : e2v[j] * K2r;
      o[j] = ((nib >> j) & 1u) ? val : 0.f;
    }
    *(fx4*)(alphap + arow + i0) = o;
  }
}

// ---- K5c: out = alpha@Wi via MFMA, no alpha stores, explicit WiT double-buffer.
// grid 512 x 512 thr; block owns 16 rows; wave wv does k-steps wv+8m.
__global__ __launch_bounds__(512, 3) void k_out(
    const unsigned* __restrict__ mask, const float* __restrict__ a1g,
    const float* __restrict__ e1g, const float* __restrict__ e2g,
    const unsigned* __restrict__ mxenc, const float* __restrict__ rinv,
    const short* __restrict__ WiT, float* __restrict__ outp)
{
  __shared__ __align__(16) float cop[4 * 2112];   // epilogue only
  const int tid  = threadIdx.x;
  const int lane = tid & 63;
  const int wv   = tid >> 6;
  const int u0 = blockIdx.x * 16;
  const int lr = lane & 15;
  const int lg = lane >> 4;
  const float A  = a1g[u0 + lr];
  const float C  = lrelu(A + fdec(mxenc[0]));
  const float K1 = __expf(A - C);
  const float K2 = __expf(0.2f * A - C);
  const float T1 = __expf(-A);
  const unsigned* mrow = mask + (size_t)(u0 + lr) * 256;
  const short* wbase = WiT + (size_t)lr * NI + lg * 8;

  fx4 acc[8];
#pragma unroll
  for (int n = 0; n < 8; ++n) acc[n] = (fx4){0.f, 0.f, 0.f, 0.f};

  bx8 bufA[8], bufB[8];
  {
    const int io = wv * 32;
#pragma unroll
    for (int n = 0; n < 8; ++n)
      bufA[n] = *(const bx8*)(wbase + (size_t)n * 16 * NI + io);
  }

#define KSTEP(BUFCUR, BUFNXT, KS, PREF)                                        \
  {                                                                            \
    const int ks = (KS);                                                       \
    if (PREF) {                                                                \
      const int ion = (ks + 8) * 32;                                           \
      _Pragma("unroll")                                                        \
      for (int n = 0; n < 8; ++n)                                              \
        BUFNXT[n] = *(const bx8*)(wbase + (size_t)n * 16 * NI + ion);          \
    }                                                                          \
    const int io = ks * 32 + lg * 8;                                           \
    const unsigned by = (mrow[ks] >> (lg * 8)) & 0xFFu;                        \
    const fx4 e1a = *(const fx4*)(e1g + io);                                   \
    const fx4 e1b = *(const fx4*)(e1g + io + 4);                               \
    const fx4 e2a = *(const fx4*)(e2g + io);                                   \
    const fx4 e2b = *(const fx4*)(e2g + io + 4);                               \
    bx8 af;                                                                    \
    _Pragma("unroll")                                                          \
    for (int j = 0; j < 8; ++j) {                                              \
      const float e1v = (j < 4) ? e1a[j] : e1b[j - 4];                         \
      const float e2v = (j < 4) ? e2a[j] : e2b[j - 4];                         \
      const float val = (e1v > T1) ? e1v * K1 : e2v * K2;                      \
      af[j] = ((by >> j) & 1u) ? f2bf(val) : (short)0;                         \
    }                                                                          \
    _Pragma("unroll")                                                          \
    for (int n = 0; n < 8; ++n)                                                \
      acc[n] = __builtin_amdgcn_mfma_f32_16x16x32_bf16(af, BUFCUR[n], acc[n],  \
                                                       0, 0, 0);               \
  }

  for (int m = 0; m < 32; m += 2) {
    KSTEP(bufA, bufB, wv + m * 8, true);
    KSTEP(bufB, bufA, wv + (m + 1) * 8, (m + 2 < 32));
  }
#undef KSTEP

  // ---- Epilogue: reduce 8 wave-partials via 4 LDS copies (stride-132 pad) ----
  float* my = cop + (size_t)(wv & 3) * 2112;
  if (wv < 4) {
#pragma unroll
    for (int n = 0; n < 8; ++n)
#pragma unroll
      for (int v = 0; v < 4; ++v)
        my[(lg * 4 + v) * 132 + n * 16 + lr] = acc[n][v];
  }
  __syncthreads();
  if (wv >= 4) {
#pragma unroll
    for (int n = 0; n < 8; ++n)
#pragma unroll
      for (int v = 0; v < 4; ++v)
        my[(lg * 4 + v) * 132 + n * 16 + lr] += acc[n][v];
  }
  __syncthreads();
  {
    const int r  = tid >> 5;          // 0..15
    const int c0 = (tid & 31) * 4;    // 0..124
    const float ri_fin = rinv[u0 + r];
    fx4 s = *(const fx4*)(cop + r * 132 + c0);
#pragma unroll
    for (int cc = 1; cc < 4; ++cc) {
      fx4 t = *(const fx4*)(cop + cc * 2112 + r * 132 + c0);
      s[0] += t[0]; s[1] += t[1]; s[2] += t[2]; s[3] += t[3];
    }
    fx4 o;
#pragma unroll
    for (int e = 0; e < 4; ++e) o[e] = s[e] * ri_fin;
    *(fx4*)(outp + (size_t)(u0 + r) * DD + c0) = o;
  }
}

extern "C" void kernel_launch(void* const* d_in, const int* in_sizes, int n_in,
                              void* d_out, int out_size, void* d_ws, size_t ws_size,
                              hipStream_t stream) {
  (void)in_sizes; (void)n_in; (void)out_size; (void)ws_size;
  const float* h_u = (const float*)d_in[0];
  const float* h_i = (const float*)d_in[1];
  const int*   adj = (const int*)d_in[2];
  const float* W   = (const float*)d_in[3];
  const float* a   = (const float*)d_in[4];

  float* outp   = (float*)d_out;                       // [8192][128]
  float* alphap = (float*)d_out + (size_t)NU * DD;     // [8192][8192]

  char* ws = (char*)d_ws;
  float*    v1    = (float*)(ws + 0);          // 128 f32
  float*    v2    = (float*)(ws + 512);        // 128 f32
  unsigned* mxenc = (unsigned*)(ws + 1024);    // 1 u32 (order-encoded max a2)
  float*    a1    = (float*)(ws + 4096);       // 8192 f32
  float*    a2    = (float*)(ws + 36864);      // 8192 f32
  float*    rinv  = (float*)(ws + 69632);      // 8192 f32
  float*    e1t   = (float*)(ws + 102400);     // 8192 f32: exp(a2)
  float*    e2t   = (float*)(ws + 135168);     // 8192 f32: exp(0.2 a2)
  short*    WiT   = (short*)(ws + 262144);     // 128*8192 bf16 = 2 MiB
  unsigned* mask  = (unsigned*)(ws + 2359296); // 8192*256 u32 = 8 MiB

  k_vecs   <<<1,   128, 0, stream>>>(W, a, v1, v2, mxenc);
  k_rowdots<<<64,  256, 0, stream>>>(h_u, h_i, v1, v2, a1, a2, e1t, e2t, mxenc);
  k_wit    <<<128, 256, 0, stream>>>(h_i, W, WiT);
  k_phaseA <<<NU,  512, 0, stream>>>(adj, a1, e1t, e2t, mxenc, rinv,
                                     (unsigned short*)mask);
  k_alpha  <<<2048, 512, 0, stream>>>(mask, a1, mxenc, rinv, e1t, e2t, alphap);
  k_out    <<<512,  512, 0, stream>>>(mask, a1, e1t, e2t, mxenc, rinv, WiT, outp);
}

// Round 6
// 315.465 us; speedup vs baseline: 1.0962x; 1.0962x over previous
//
#include <hip/hip_runtime.h>

#define NU 8192
#define NI 8192
#define DD 128

typedef float fx4 __attribute__((ext_vector_type(4)));
typedef int   ix4 __attribute__((ext_vector_type(4)));
typedef short bx8 __attribute__((ext_vector_type(8)));
typedef short sx4 __attribute__((ext_vector_type(4)));

__device__ __forceinline__ short f2bf(float f) {
  unsigned u = __float_as_uint(f);
  u = (u + 0x7FFFu + ((u >> 16) & 1u)) >> 16;   // RNE f32 -> bf16
  return (short)u;
}
__device__ __forceinline__ float lrelu(float x) { return fmaxf(x, 0.2f * x); }
// order-preserving float<->uint encode for atomicMax (deterministic: max assoc/comm)
__device__ __forceinline__ unsigned fenc(float f) {
  unsigned u = __float_as_uint(f);
  return (u >> 31) ? ~u : (u | 0x80000000u);
}
__device__ __forceinline__ float fdec(unsigned u) {
  return (u >> 31) ? __uint_as_float(u & 0x7FFFFFFFu) : __uint_as_float(~u);
}

// ---- K1: v1[j] = sum_k a[k]*W[k][j] ; v2[j] = sum_k a[128+k]*W[k][j]; init mxenc
__global__ void k_vecs(const float* __restrict__ W, const float* __restrict__ a,
                       float* __restrict__ v1, float* __restrict__ v2,
                       unsigned* __restrict__ mxenc) {
  int j = threadIdx.x;  // 128 threads
  if (j == 0) mxenc[0] = 0u;
  float s1 = 0.f, s2 = 0.f;
  for (int k = 0; k < DD; ++k) {
    float w = W[k * DD + j];
    s1 += a[k] * w;
    s2 += a[DD + k] * w;
  }
  v1[j] = s1; v2[j] = s2;
}

// ---- K2: a1[u]=h_u·v1 ; a2[i]=h_i·v2 ; E1=exp(a2), E2=exp(0.2 a2); atomicMax a2
__global__ __launch_bounds__(256) void k_rowdots(
    const float* __restrict__ hU, const float* __restrict__ hI,
    const float* __restrict__ v1, const float* __restrict__ v2,
    float* __restrict__ a1, float* __restrict__ a2,
    float* __restrict__ e1, float* __restrict__ e2,
    unsigned* __restrict__ mxenc) {
  __shared__ float red[256];
  int g = blockIdx.x * 256 + threadIdx.x;
  const float* h; const float* v; int row;
  bool isU = (g < NU);
  if (isU) { h = hU; v = v1; row = g; }
  else     { h = hI; v = v2; row = g - NU; }
  const fx4* hv = (const fx4*)(h + (size_t)row * DD);
  const fx4* vv = (const fx4*)v;
  float s = 0.f;
#pragma unroll
  for (int q = 0; q < DD / 4; ++q) {
    fx4 hq = hv[q], vq = vv[q];
    s += hq[0]*vq[0] + hq[1]*vq[1] + hq[2]*vq[2] + hq[3]*vq[3];
  }
  if (isU) { a1[row] = s; return; }           // blocks 0..31 all-user: uniform exit
  a2[row] = s;
  e1[row] = __expf(s);
  e2[row] = __expf(0.2f * s);
  red[threadIdx.x] = s;
  __syncthreads();
  for (int st = 128; st > 0; st >>= 1) {
    if (threadIdx.x < st) red[threadIdx.x] = fmaxf(red[threadIdx.x], red[threadIdx.x + st]);
    __syncthreads();
  }
  if (threadIdx.x == 0) atomicMax(mxenc, fenc(red[0]));
}

// ---- K4: WiT[k][i] (bf16) = Wi[i][k] = sum_j h_i[i][j]*W[k][j]
__global__ __launch_bounds__(256) void k_wit(const float* __restrict__ hI,
                                             const float* __restrict__ W,
                                             short* __restrict__ WiT) {
  __shared__ float Wl[128 * 128];
  const int tid = threadIdx.x;
#pragma unroll
  for (int it = 0; it < 16; ++it) {
    int idx = it * 1024 + tid * 4;
    *(fx4*)(Wl + idx) = *(const fx4*)(W + idx);
  }
  __syncthreads();
  const int i0 = blockIdx.x * 64;
  const int rg = tid & 15;
  const int kg = tid >> 4;
  const int r0 = i0 + rg * 4;
  const int k0 = kg * 8;
  float acc[4][8];
#pragma unroll
  for (int r = 0; r < 4; ++r)
#pragma unroll
    for (int c = 0; c < 8; ++c) acc[r][c] = 0.f;
  for (int j = 0; j < 128; j += 4) {
    fx4 wv[8], hv[4];
#pragma unroll
    for (int c = 0; c < 8; ++c) wv[c] = *(const fx4*)(Wl + (k0 + c) * 128 + j);
#pragma unroll
    for (int r = 0; r < 4; ++r) hv[r] = *(const fx4*)(hI + (size_t)(r0 + r) * DD + j);
#pragma unroll
    for (int r = 0; r < 4; ++r)
#pragma unroll
      for (int c = 0; c < 8; ++c)
        acc[r][c] += hv[r][0]*wv[c][0] + hv[r][1]*wv[c][1] + hv[r][2]*wv[c][2] + hv[r][3]*wv[c][3];
  }
#pragma unroll
  for (int c = 0; c < 8; ++c) {
    sx4 pk;
#pragma unroll
    for (int r = 0; r < 4; ++r) pk[r] = f2bf(acc[r][c]);
    *(sx4*)(WiT + (size_t)(k0 + c) * NI + r0) = pk;
  }
}

// ---- K5a: stream adj once -> bitmask + rinv. 1 row/block, 512 thr, low VGPR.
__global__ __launch_bounds__(512, 4) void k_phaseA(
    const int* __restrict__ adj, const float* __restrict__ a1g,
    const float* __restrict__ e1g, const float* __restrict__ e2g,
    const unsigned* __restrict__ mxenc,
    float* __restrict__ rinv, unsigned short* __restrict__ mask16)
{
  const int row  = blockIdx.x;
  const int tid  = threadIdx.x;
  const int lane = tid & 63;
  const int wv   = tid >> 6;
  const float A  = a1g[row];
  const float C  = lrelu(A + fdec(mxenc[0]));
  const float K1 = __expf(A - C);
  const float K2 = __expf(0.2f * A - C);
  const float T1 = __expf(-A);          // sel <=> E1[i] > T1 <=> a1+a2 > 0
  const int i0 = tid * 16;
  const size_t base = (size_t)row * NI + i0;
  ix4 m[4]; fx4 E1[4], E2[4];
#pragma unroll
  for (int q = 0; q < 4; ++q) {
    m[q]  = __builtin_nontemporal_load((const ix4*)(adj + base + q * 4));
    E1[q] = *(const fx4*)(e1g + i0 + q * 4);
    E2[q] = *(const fx4*)(e2g + i0 + q * 4);
  }
  unsigned hw = 0u;
  float s1 = 0.f, s2 = 0.f;
#pragma unroll
  for (int q = 0; q < 4; ++q) {
#pragma unroll
    for (int e = 0; e < 4; ++e) {
      const bool mm = (m[q][e] != 0);
      const bool sel = (E1[q][e] > T1);
      if (mm) hw |= (1u << (q * 4 + e));
      s1 += (mm && sel)  ? E1[q][e] : 0.f;
      s2 += (mm && !sel) ? E2[q][e] : 0.f;
    }
  }
  mask16[(size_t)row * 512 + tid] = (unsigned short)hw;
  float ps = K1 * s1 + K2 * s2;
#pragma unroll
  for (int st = 1; st < 64; st <<= 1) ps += __shfl_xor(ps, st, 64);
  __shared__ float lp[8];
  if (lane == 0) lp[wv] = ps;
  __syncthreads();
  if (tid == 0) {
    float l = 0.f;
#pragma unroll
    for (int w = 0; w < 8; ++w) l += lp[w];
    rinv[row] = (l > 0.f) ? (1.f / l) : 0.f;
  }
}

// ---- K5b: fused alpha + out-partial GEMM with LDS-staged B.
// grid 512 = 128 uTiles x 4 K-quarters; 512 thr (8 waves = 4 wm x 2 wn).
// Block: rows u0..u0+64, i-range q*2048..+2048. BK=64, 32 chunks, dbuf LDS 32KB.
__global__ __launch_bounds__(512, 4) void k_big(
    const unsigned* __restrict__ mask, const float* __restrict__ a1g,
    const float* __restrict__ e1g, const float* __restrict__ e2g,
    const unsigned* __restrict__ mxenc, const float* __restrict__ rinv,
    const short* __restrict__ WiT, float* __restrict__ partial,
    float* __restrict__ alphap)
{
  __shared__ __align__(16) char lds[32768];
  const int tid  = threadIdx.x;
  const int lane = tid & 63;
  const int wv   = tid >> 6;
  const int wm   = wv & 3;         // m-frag (16 rows each)
  const int wn   = wv >> 1 & 0;    // placeholder to avoid confusion
  const int wn2  = wv >> 2;        // 0..1: n-half (64 cols each)
  const int uTile = (int)blockIdx.x >> 2;
  const int quar  = (int)blockIdx.x & 3;
  const int u0 = uTile * 64;
  const int ib = quar * 2048;
  const int lr = lane & 15, lg = lane >> 4;
  const int row = u0 + wm * 16 + lr;
  const float A  = a1g[row];
  const float C  = lrelu(A + fdec(mxenc[0]));
  const float K1 = __expf(A - C);
  const float K2 = __expf(0.2f * A - C);
  const float T1 = __expf(-A);
  const float ri = rinv[row];
  const unsigned* mrow = mask + (size_t)row * 256 + quar * 64;
  float* arow = alphap + (size_t)row * NI + ib;

  // staging map: thread covers (d = tid>>3 and d+64, i8 = tid&7)
  const int sd = tid >> 3;
  const int si = tid & 7;
  const short* g0 = WiT + (size_t)sd * NI + ib + si * 8;
  const short* g1 = WiT + (size_t)(sd + 64) * NI + ib + si * 8;
  const int swz = (si * 16) ^ ((sd & 7) << 4);
  const int w0 = sd * 128 + swz;
  const int w1 = (sd + 64) * 128 + swz;

  fx4 acc[4];
#pragma unroll
  for (int n = 0; n < 4; ++n) acc[n] = (fx4){0.f, 0.f, 0.f, 0.f};

  // prolog: stage chunk 0 into buf0
  bx8 sA = *(const bx8*)g0;
  bx8 sB = *(const bx8*)g1;
  *(bx8*)(lds + w0) = sA;
  *(bx8*)(lds + w1) = sB;

  for (int c = 0; c < 32; ++c) {
    char* buf = lds + (c & 1) * 16384;
    const int nxt = ((c + 1) & 1) * 16384;
    if (c < 31) {                       // issue next-chunk loads early
      sA = *(const bx8*)(g0 + (c + 1) * 64);
      sB = *(const bx8*)(g1 + (c + 1) * 64);
    }
    __syncthreads();                    // buf[c&1] ready; prior reads of nxt done
#pragma unroll
    for (int ks = 0; ks < 2; ++ks) {
      const int ksg = c * 2 + ks;       // 0..63 (32-i steps within quarter)
      const unsigned by = (mrow[ksg] >> (lg * 8)) & 0xFFu;
      const int io = ksg * 32 + lg * 8; // i offset within quarter
      const fx4 e1a = *(const fx4*)(e1g + ib + io);
      const fx4 e1b = *(const fx4*)(e1g + ib + io + 4);
      const fx4 e2a = *(const fx4*)(e2g + ib + io);
      const fx4 e2b = *(const fx4*)(e2g + ib + io + 4);
      float p[8];
#pragma unroll
      for (int j = 0; j < 8; ++j) {
        const float e1v = (j < 4) ? e1a[j] : e1b[j - 4];
        const float e2v = (j < 4) ? e2a[j] : e2b[j - 4];
        const float val = (e1v > T1) ? e1v * K1 : e2v * K2;
        p[j] = ((by >> j) & 1u) ? val : 0.f;
      }
      // fused normalized-alpha store: wn2 picks which fx4 half this wave writes
      fx4 sv;
#pragma unroll
      for (int j = 0; j < 4; ++j) sv[j] = p[wn2 * 4 + j] * ri;
      *(fx4*)(arow + io + wn2 * 4) = sv;
      bx8 af;
#pragma unroll
      for (int j = 0; j < 8; ++j) af[j] = f2bf(p[j]);
#pragma unroll
      for (int nf = 0; nf < 4; ++nf) {
        const int d = wn2 * 64 + nf * 16 + lr;
        const bx8 bf = *(const bx8*)(buf + d * 128 +
                        ((ks * 64 + lg * 16) ^ ((lr & 7) << 4)));
        acc[nf] = __builtin_amdgcn_mfma_f32_16x16x32_bf16(af, bf, acc[nf], 0, 0, 0);
      }
    }
    if (c < 31) {                       // write next chunk (compiler waits vmcnt)
      *(bx8*)(lds + nxt + w0) = sA;
      *(bx8*)(lds + nxt + w1) = sB;
    }
  }

  // epilogue: waves own disjoint 16x64 tiles -> store partial directly
  float* pb = partial + (size_t)blockIdx.x * (64 * 128);
#pragma unroll
  for (int nf = 0; nf < 4; ++nf)
#pragma unroll
    for (int v = 0; v < 4; ++v)
      pb[(wm * 16 + lg * 4 + v) * 128 + wn2 * 64 + nf * 16 + lr] = acc[nf][v];
}

// ---- K5c: out[u][d] = (sum of 4 K-quarter partials) * rinv[u]
__global__ __launch_bounds__(512) void k_comb(
    const float* __restrict__ partial, const float* __restrict__ rinv,
    float* __restrict__ outp)
{
  const int g = blockIdx.x * 512 + threadIdx.x;   // 0..262143 (fx4 units)
  const int u = g >> 5;
  const int c4 = (g & 31) * 4;
  const int uTile = u >> 6, r = u & 63;
  const float* p0 = partial + ((size_t)uTile * 4) * 8192 + r * 128 + c4;
  fx4 s = *(const fx4*)p0;
#pragma unroll
  for (int q = 1; q < 4; ++q) {
    fx4 t = *(const fx4*)(p0 + (size_t)q * 8192);
    s[0] += t[0]; s[1] += t[1]; s[2] += t[2]; s[3] += t[3];
  }
  const float ri = rinv[u];
  fx4 o;
#pragma unroll
  for (int e = 0; e < 4; ++e) o[e] = s[e] * ri;
  *(fx4*)(outp + (size_t)u * DD + c4) = o;
}

extern "C" void kernel_launch(void* const* d_in, const int* in_sizes, int n_in,
                              void* d_out, int out_size, void* d_ws, size_t ws_size,
                              hipStream_t stream) {
  (void)in_sizes; (void)n_in; (void)out_size; (void)ws_size;
  const float* h_u = (const float*)d_in[0];
  const float* h_i = (const float*)d_in[1];
  const int*   adj = (const int*)d_in[2];
  const float* W   = (const float*)d_in[3];
  const float* a   = (const float*)d_in[4];

  float* outp   = (float*)d_out;                       // [8192][128]
  float* alphap = (float*)d_out + (size_t)NU * DD;     // [8192][8192]

  char* ws = (char*)d_ws;
  float*    v1    = (float*)(ws + 0);          // 128 f32
  float*    v2    = (float*)(ws + 512);        // 128 f32
  unsigned* mxenc = (unsigned*)(ws + 1024);    // 1 u32 (order-encoded max a2)
  float*    a1    = (float*)(ws + 4096);       // 8192 f32
  float*    a2    = (float*)(ws + 36864);      // 8192 f32
  float*    rinv  = (float*)(ws + 69632);      // 8192 f32
  float*    e1t   = (float*)(ws + 102400);     // 8192 f32: exp(a2)
  float*    e2t   = (float*)(ws + 135168);     // 8192 f32: exp(0.2 a2)
  short*    WiT   = (short*)(ws + 262144);     // 128*8192 bf16 = 2 MiB
  unsigned* mask  = (unsigned*)(ws + 2359296); // 8192*256 u32 = 8 MiB
  float*    part  = (float*)(ws + 11534336);   // 512*64*128 f32 = 16 MiB

  k_vecs   <<<1,   128, 0, stream>>>(W, a, v1, v2, mxenc);
  k_rowdots<<<64,  256, 0, stream>>>(h_u, h_i, v1, v2, a1, a2, e1t, e2t, mxenc);
  k_wit    <<<128, 256, 0, stream>>>(h_i, W, WiT);
  k_phaseA <<<NU,  512, 0, stream>>>(adj, a1, e1t, e2t, mxenc, rinv,
                                     (unsigned short*)mask);
  k_big    <<<512, 512, 0, stream>>>(mask, a1, e1t, e2t, mxenc, rinv, WiT,
                                     part, alphap);
  k_comb   <<<512, 512, 0, stream>>>(part, rinv, outp);
}